// Round 8
// baseline (13488.768 us; speedup 1.0000x reference)
//
#include <hip/hip_runtime.h>

// LSTM B=32 T=2048 I=H=512. out = h_T [1,32,512] f32.
// p1: x_proj chunk GEMM (bf16 MFMA) -> xp[t_local*32+b][4H] bf16 (bias folded).
// p2: persistent recurrence, 32 blocks, FENCE-FREE tagged exchange.
//   H32: 4 slots x [batch 32][unit 512] u32, word = (bf16 h)<<16 | step-tag.
//   Producer: 2 relaxed agent atomic u32 stores per lane, fire-and-proceed
//   (no drain, no flag). Consumer: 32 relaxed agent atomic u64 loads per
//   thread (pipelined), per-thread predicated retry of stale words only,
//   unpack into double-buffered swizzled LDS, ONE barrier/step, MFMA from
//   LDS, quad-shfl gates. No fences anywhere in the loop.

#define T_FULL 2048
#define CHUNK  256
#define NCHUNK 8
#define NBLK   32

typedef float  f32x4 __attribute__((ext_vector_type(4)));
typedef short  s16x8 __attribute__((ext_vector_type(8)));
typedef unsigned int u32;
typedef unsigned long long u64;

#define MFMA16(a,b,c) __builtin_amdgcn_mfma_f32_16x16x32_bf16((a),(b),(c),0,0,0)

__device__ inline unsigned short f2bf(float f){
  unsigned u = __builtin_bit_cast(unsigned, f);
  u += 0x7fffu + ((u>>16)&1u);          // RNE
  return (unsigned short)(u>>16);
}
__device__ inline float bf2f(unsigned short s){
  unsigned u = ((unsigned)s)<<16;
  return __builtin_bit_cast(float, u);
}
__device__ inline float sigmoid_(float x){
  x = fminf(fmaxf(x,-30.f),30.f);
  return 1.f/(1.f + __expf(-x));
}
__device__ inline float tanh_(float x){
  x = fminf(fmaxf(x,-15.f),15.f);
  float e = __expf(2.f*x);
  return (e-1.f)/(e+1.f);
}

// ---------------- Phase 1: x_proj chunk GEMM ----------------
__global__ __launch_bounds__(256) void lstm_p1(
    const float* __restrict__ x, const float* __restrict__ Wih,
    const float* __restrict__ bih, const float* __restrict__ bhh,
    unsigned short* __restrict__ xp, int t0)
{
  __shared__ __align__(16) unsigned short At[64*136];
  __shared__ __align__(16) unsigned short Bt[64*136];
  const int tid = threadIdx.x, lane = tid&63, w = tid>>6;
  const int l15 = lane&15, l4 = lane>>4;
  const int n0 = blockIdx.x*64, m0 = blockIdx.y*64;
  const int mbase = (w&1)*32, nbase = (w>>1)*32;

  f32x4 acc[2][2];
  #pragma unroll
  for (int mi=0; mi<2; ++mi)
    #pragma unroll
    for (int ni=0; ni<2; ++ni)
      acc[mi][ni] = (f32x4){0.f,0.f,0.f,0.f};

  for (int kb=0; kb<4; ++kb){
    #pragma unroll
    for (int it=0; it<4; ++it){
      int grp = it*256 + tid;            // 0..1023
      int row = grp>>4, c8 = (grp&15)*8; // 16 groups of 8 per row
      {
        int m = m0 + row;
        size_t t = (size_t)t0 + (m>>5), b = (size_t)(m&31);
        const float* src = x + ((b*2048 + t)<<9) + kb*128 + c8;
        f32x4 v0 = *(const f32x4*)src, v1 = *(const f32x4*)(src+4);
        unsigned short* d = &At[row*136 + c8];
        d[0]=f2bf(v0[0]); d[1]=f2bf(v0[1]); d[2]=f2bf(v0[2]); d[3]=f2bf(v0[3]);
        d[4]=f2bf(v1[0]); d[5]=f2bf(v1[1]); d[6]=f2bf(v1[2]); d[7]=f2bf(v1[3]);
      }
      {
        const float* src = Wih + (size_t)(n0+row)*512 + kb*128 + c8;
        f32x4 v0 = *(const f32x4*)src, v1 = *(const f32x4*)(src+4);
        unsigned short* d = &Bt[row*136 + c8];
        d[0]=f2bf(v0[0]); d[1]=f2bf(v0[1]); d[2]=f2bf(v0[2]); d[3]=f2bf(v0[3]);
        d[4]=f2bf(v1[0]); d[5]=f2bf(v1[1]); d[6]=f2bf(v1[2]); d[7]=f2bf(v1[3]);
      }
    }
    __syncthreads();
    #pragma unroll
    for (int ks=0; ks<4; ++ks){
      s16x8 af0 = *(const s16x8*)&At[(mbase+   l15)*136 + ks*32 + l4*8];
      s16x8 af1 = *(const s16x8*)&At[(mbase+16+l15)*136 + ks*32 + l4*8];
      s16x8 bf0 = *(const s16x8*)&Bt[(nbase+   l15)*136 + ks*32 + l4*8];
      s16x8 bf1 = *(const s16x8*)&Bt[(nbase+16+l15)*136 + ks*32 + l4*8];
      acc[0][0] = MFMA16(af0,bf0,acc[0][0]);
      acc[0][1] = MFMA16(af0,bf1,acc[0][1]);
      acc[1][0] = MFMA16(af1,bf0,acc[1][0]);
      acc[1][1] = MFMA16(af1,bf1,acc[1][1]);
    }
    __syncthreads();
  }
  #pragma unroll
  for (int ni=0; ni<2; ++ni){
    int col = n0 + nbase + ni*16 + l15;
    float bias = bih[col] + bhh[col];
    #pragma unroll
    for (int mi=0; mi<2; ++mi){
      #pragma unroll
      for (int r=0; r<4; ++r){
        int mrow = m0 + mbase + mi*16 + l4*4 + r;
        xp[(size_t)mrow*2048 + col] = f2bf(acc[mi][ni][r] + bias);
      }
    }
  }
}

// ---------------- Phase 2: recurrence (fence-free tagged exchange) ----------
__global__ __launch_bounds__(256,1) void lstm_p2(
    const unsigned short* __restrict__ xp, const float* __restrict__ Whh,
    u32* __restrict__ H32, float* __restrict__ cst,
    float* __restrict__ out, int t0)
{
  const int k = blockIdx.x;
  const int tid = threadIdx.x;
  const int lane = tid & 63, w = tid >> 6;
  const int l15 = lane & 15, l4 = lane >> 4;
  const int g = l15 & 3;                        // lane's gate
  const int U = k*16 + w*4 + (l15 >> 2);        // lane's global hidden unit
  const int gcol = g*512 + U;                   // xp column of this gate-row
  const int q = g;                              // quad member -> 2 publish batches
  const int bq = (q>>1)*16 + l4*4 + (q&1)*2;

  __shared__ __align__(16) char HlBuf[2*32*1024];

  // W_hh B-fragments: wave's 16 gate rows, n=l15 -> W row g*512+U
  s16x8 wf[16];
  {
    const float* wr = Whh + (size_t)(g*512 + U)*512;
    #pragma unroll
    for (int ks=0; ks<16; ++ks){
      const float* s = wr + ks*32 + l4*8;
      f32x4 v0 = *(const f32x4*)s, v1 = *(const f32x4*)(s+4);
      s16x8 tt;
      tt[0]=(short)f2bf(v0[0]); tt[1]=(short)f2bf(v0[1]);
      tt[2]=(short)f2bf(v0[2]); tt[3]=(short)f2bf(v0[3]);
      tt[4]=(short)f2bf(v1[0]); tt[5]=(short)f2bf(v1[1]);
      tt[6]=(short)f2bf(v1[2]); tt[7]=(short)f2bf(v1[3]);
      wf[ks] = tt;
    }
  }

  // c-state restore (quad-redundant)
  float c[2][4];
  #pragma unroll
  for (int mt2=0; mt2<2; ++mt2)
    #pragma unroll
    for (int r=0; r<4; ++r)
      c[mt2][r] = cst[(size_t)(mt2*16 + l4*4 + r)*512 + U];

  for (int tt=0; tt<CHUNK; ++tt){
    const int t = t0 + tt;
    const u32 tagc = (u32)t, tagn = (u32)(t+1);
    const u64 tag2  = (u64)tagc | ((u64)tagc << 32);
    const u64 TMASK = 0x0000ffff0000ffffULL;
    const u64* Hs64 = (const u64*)(H32 + (size_t)(t & 3)*16384);
    u32*       Hd   = H32 + (size_t)((t+1) & 3)*16384;
    char* Hl = HlBuf + (size_t)(t & 1)*32768;

    // xp gate inputs (normal cached loads; issue before the atomic storm)
    float xg[2][4];
    #pragma unroll
    for (int mt2=0; mt2<2; ++mt2)
      #pragma unroll
      for (int r=0; r<4; ++r)
        xg[mt2][r] = bf2f(xp[(size_t)(tt*32 + mt2*16 + l4*4 + r)*2048 + gcol]);

    // fetch tagged H: 32 relaxed agent atomic u64 loads (pipelined), then
    // per-thread predicated retry of stale words only. No fences.
    {
      u64 v[32];
      #pragma unroll
      for (int j=0; j<32; ++j)
        v[j] = __hip_atomic_load(&Hs64[(size_t)j*256 + tid],
                                 __ATOMIC_RELAXED, __HIP_MEMORY_SCOPE_AGENT);
      for (;;){
        u64 m = 0;
        #pragma unroll
        for (int j=0; j<32; ++j) m |= (v[j] ^ tag2) & TMASK;
        if (m == 0) break;
        #pragma unroll
        for (int j=0; j<32; ++j)
          if (((v[j] ^ tag2) & TMASK) != 0)
            v[j] = __hip_atomic_load(&Hs64[(size_t)j*256 + tid],
                                     __ATOMIC_RELAXED, __HIP_MEMORY_SCOPE_AGENT);
      }
      // unpack: batch j, units 2*tid, 2*tid+1 -> one u32 into swizzled LDS
      #pragma unroll
      for (int j=0; j<32; ++j){
        u32 pay = ((u32)(v[j] >> 16) & 0xffffu) | ((u32)(v[j] >> 32) & 0xffff0000u);
        *(u32*)(Hl + (j<<10) + (((u32)tid<<2) ^ (u32)((j&7)<<4))) = pay;
      }
    }
    __syncthreads();

    // z = h_t @ Wslice^T : 2 m-tiles x 16 ks, A from swizzled LDS
    f32x4 z[2];
    #pragma unroll
    for (int mt2=0; mt2<2; ++mt2){
      const int row = mt2*16 + l15;
      const int swz = (row&7)<<4, rb = row<<10;
      f32x4 acc = (f32x4){0.f,0.f,0.f,0.f};
      #pragma unroll
      for (int ks=0; ks<16; ++ks){
        int cb = ks*64 + l4*16;
        s16x8 af = *(const s16x8*)(Hl + (rb | (cb ^ swz)));
        acc = MFMA16(af, wf[ks], acc);
      }
      z[mt2] = acc;
    }

    // gates: quad shfl exchange (lane holds gate g of its unit, 8 batches)
    float hv[2][4];
    #pragma unroll
    for (int mt2=0; mt2<2; ++mt2){
      #pragma unroll
      for (int r=0; r<4; ++r){
        float v = z[mt2][r] + xg[mt2][r];
        float vi = __shfl_xor(v, g    );
        float vf = __shfl_xor(v, g ^ 1);
        float vg = __shfl_xor(v, g ^ 2);
        float vo = __shfl_xor(v, g ^ 3);
        float ii = sigmoid_(vi), ff = sigmoid_(vf);
        float gg = tanh_(vg),    oo = sigmoid_(vo);
        float cc = ff*c[mt2][r] + ii*gg;
        c[mt2][r] = cc;
        hv[mt2][r] = oo * tanh_(cc);
      }
    }

    // publish h_{t+1}: 2 tagged u32 atomic stores, fire-and-proceed
    {
      float ha0 = (q&1) ? hv[0][2] : hv[0][0];
      float ha1 = (q&1) ? hv[0][3] : hv[0][1];
      float hb0 = (q&1) ? hv[1][2] : hv[1][0];
      float hb1 = (q&1) ? hv[1][3] : hv[1][1];
      float h0 = (q>>1) ? hb0 : ha0;
      float h1 = (q>>1) ? hb1 : ha1;
      u32 w0 = ((u32)f2bf(h0) << 16) | tagn;
      u32 w1 = ((u32)f2bf(h1) << 16) | tagn;
      __hip_atomic_store(&Hd[(size_t)(bq  )*512 + U], w0,
                         __ATOMIC_RELAXED, __HIP_MEMORY_SCOPE_AGENT);
      __hip_atomic_store(&Hd[(size_t)(bq+1)*512 + U], w1,
                         __ATOMIC_RELAXED, __HIP_MEMORY_SCOPE_AGENT);
      if (t == T_FULL-1){
        out[(size_t)(bq  )*512 + U] = h0;
        out[(size_t)(bq+1)*512 + U] = h1;
      }
    }
  }

  // c-state save (lane's 2 assigned batches)
  {
    float ca0 = (q&1) ? c[0][2] : c[0][0];
    float ca1 = (q&1) ? c[0][3] : c[0][1];
    float cb0 = (q&1) ? c[1][2] : c[1][0];
    float cb1 = (q&1) ? c[1][3] : c[1][1];
    float c0s = (q>>1) ? cb0 : ca0;
    float c1s = (q>>1) ? cb1 : ca1;
    cst[(size_t)(bq  )*512 + U] = c0s;
    cst[(size_t)(bq+1)*512 + U] = c1s;
  }
}

// ---------------- launch ----------------
extern "C" void kernel_launch(void* const* d_in, const int* in_sizes, int n_in,
                              void* d_out, int out_size, void* d_ws, size_t ws_size,
                              hipStream_t stream)
{
  const float* x   = (const float*)d_in[0];
  const float* Wih = (const float*)d_in[1];
  const float* Whh = (const float*)d_in[2];
  const float* bih = (const float*)d_in[3];
  const float* bhh = (const float*)d_in[4];
  float* out = (float*)d_out;

  char* ws = (char*)d_ws;
  const size_t XP_BYTES = (size_t)CHUNK*32*2048*2;                 // 33,554,432
  unsigned short* xp  = (unsigned short*)ws;
  u32*            H32 = (u32*)(ws + XP_BYTES);                     // 4*64KB = 262144
  float*          cst = (float*)(ws + XP_BYTES + 262144);          // 64KB

  // zero tagged H (tag0 == h_0 == 0, all 4 slots) + c-state; replay-safe
  (void)hipMemsetAsync(H32, 0, 262144 + 65536, stream);

  for (int c=0; c<NCHUNK; ++c){
    int t0 = c*CHUNK;
    lstm_p1<<<dim3(32, CHUNK*32/64), 256, 0, stream>>>(x, Wih, bih, bhh, xp, t0);
    lstm_p2<<<NBLK, 256, 0, stream>>>(xp, Whh, H32, cst, out, t0);
  }
}

// Round 9
// 9358.315 us; speedup vs baseline: 1.4414x; 1.4414x over previous
//
#include <hip/hip_runtime.h>

// LSTM B=32 T=2048 I=H=512. out = h_T [1,32,512] f32.
// p1: x_proj chunk GEMM (bf16 MFMA) -> xp[t_local*32+b][4H] bf16 (bias folded).
// p2: persistent recurrence, 32 blocks. R3's proven flag protocol
//   (producer: relaxed atomic h-stores -> vmcnt(0) -> barrier -> flag;
//    consumer: relaxed flag poll) but NO acquire fence: H fetched with
//   device-coherent global_load_dwordx4 sc0 sc1 (L1/L2 bypass = always fresh,
//   pipelined). All 4 waves poll independently (no poll barrier). Gate rows
//   unit*4+gate; quad-shfl gate combine (no zl LDS). 2 barriers/step.

#define T_FULL 2048
#define CHUNK  256
#define NCHUNK 8
#define NBLK   32

typedef float  f32x4 __attribute__((ext_vector_type(4)));
typedef short  s16x8 __attribute__((ext_vector_type(8)));
typedef unsigned int u32;

#define MFMA16(a,b,c) __builtin_amdgcn_mfma_f32_16x16x32_bf16((a),(b),(c),0,0,0)

__device__ inline unsigned short f2bf(float f){
  unsigned u = __builtin_bit_cast(unsigned, f);
  u += 0x7fffu + ((u>>16)&1u);          // RNE
  return (unsigned short)(u>>16);
}
__device__ inline float bf2f(unsigned short s){
  unsigned u = ((unsigned)s)<<16;
  return __builtin_bit_cast(float, u);
}
__device__ inline float sigmoid_(float x){
  x = fminf(fmaxf(x,-30.f),30.f);
  return 1.f/(1.f + __expf(-x));
}
__device__ inline float tanh_(float x){
  x = fminf(fmaxf(x,-15.f),15.f);
  float e = __expf(2.f*x);
  return (e-1.f)/(e+1.f);
}

// ---------------- Phase 1: x_proj chunk GEMM ----------------
__global__ __launch_bounds__(256) void lstm_p1(
    const float* __restrict__ x, const float* __restrict__ Wih,
    const float* __restrict__ bih, const float* __restrict__ bhh,
    unsigned short* __restrict__ xp, int t0)
{
  __shared__ __align__(16) unsigned short At[64*136];
  __shared__ __align__(16) unsigned short Bt[64*136];
  const int tid = threadIdx.x, lane = tid&63, w = tid>>6;
  const int l15 = lane&15, l4 = lane>>4;
  const int n0 = blockIdx.x*64, m0 = blockIdx.y*64;
  const int mbase = (w&1)*32, nbase = (w>>1)*32;

  f32x4 acc[2][2];
  #pragma unroll
  for (int mi=0; mi<2; ++mi)
    #pragma unroll
    for (int ni=0; ni<2; ++ni)
      acc[mi][ni] = (f32x4){0.f,0.f,0.f,0.f};

  for (int kb=0; kb<4; ++kb){
    #pragma unroll
    for (int it=0; it<4; ++it){
      int grp = it*256 + tid;            // 0..1023
      int row = grp>>4, c8 = (grp&15)*8; // 16 groups of 8 per row
      {
        int m = m0 + row;
        size_t t = (size_t)t0 + (m>>5), b = (size_t)(m&31);
        const float* src = x + ((b*2048 + t)<<9) + kb*128 + c8;
        f32x4 v0 = *(const f32x4*)src, v1 = *(const f32x4*)(src+4);
        unsigned short* d = &At[row*136 + c8];
        d[0]=f2bf(v0[0]); d[1]=f2bf(v0[1]); d[2]=f2bf(v0[2]); d[3]=f2bf(v0[3]);
        d[4]=f2bf(v1[0]); d[5]=f2bf(v1[1]); d[6]=f2bf(v1[2]); d[7]=f2bf(v1[3]);
      }
      {
        const float* src = Wih + (size_t)(n0+row)*512 + kb*128 + c8;
        f32x4 v0 = *(const f32x4*)src, v1 = *(const f32x4*)(src+4);
        unsigned short* d = &Bt[row*136 + c8];
        d[0]=f2bf(v0[0]); d[1]=f2bf(v0[1]); d[2]=f2bf(v0[2]); d[3]=f2bf(v0[3]);
        d[4]=f2bf(v1[0]); d[5]=f2bf(v1[1]); d[6]=f2bf(v1[2]); d[7]=f2bf(v1[3]);
      }
    }
    __syncthreads();
    #pragma unroll
    for (int ks=0; ks<4; ++ks){
      s16x8 af0 = *(const s16x8*)&At[(mbase+   l15)*136 + ks*32 + l4*8];
      s16x8 af1 = *(const s16x8*)&At[(mbase+16+l15)*136 + ks*32 + l4*8];
      s16x8 bf0 = *(const s16x8*)&Bt[(nbase+   l15)*136 + ks*32 + l4*8];
      s16x8 bf1 = *(const s16x8*)&Bt[(nbase+16+l15)*136 + ks*32 + l4*8];
      acc[0][0] = MFMA16(af0,bf0,acc[0][0]);
      acc[0][1] = MFMA16(af0,bf1,acc[0][1]);
      acc[1][0] = MFMA16(af1,bf0,acc[1][0]);
      acc[1][1] = MFMA16(af1,bf1,acc[1][1]);
    }
    __syncthreads();
  }
  #pragma unroll
  for (int ni=0; ni<2; ++ni){
    int col = n0 + nbase + ni*16 + l15;
    float bias = bih[col] + bhh[col];
    #pragma unroll
    for (int mi=0; mi<2; ++mi){
      #pragma unroll
      for (int r=0; r<4; ++r){
        int mrow = m0 + mbase + mi*16 + l4*4 + r;
        xp[(size_t)mrow*2048 + col] = f2bf(acc[mi][ni][r] + bias);
      }
    }
  }
}

// ---------------- Phase 2: recurrence (flags + coherent fetch) ----------
// Hbuf: 4 slots x [batch 32][unit 512] bf16 (32KB/slot). flag[k*32]: u32 = t+1.
__global__ __launch_bounds__(256,1) void lstm_p2(
    const unsigned short* __restrict__ xp, const float* __restrict__ Whh,
    unsigned short* __restrict__ Hbuf, float* __restrict__ cst,
    u32* __restrict__ flag, float* __restrict__ out, int t0)
{
  const int k = blockIdx.x;
  const int tid = threadIdx.x;
  const int lane = tid & 63, w = tid >> 6;
  const int l15 = lane & 15, l4 = lane >> 4;
  const int g = l15 & 3;                        // lane's gate (= quad member q)
  const int uq = l15 >> 2;
  const int U = k*16 + w*4 + uq;                // lane's global hidden unit
  const int gcol = g*512 + U;                   // xp column of this gate-row
  const int bq = (g>>1)*16 + l4*4 + (g&1)*2;    // lane's 2 publish batches

  __shared__ __align__(16) char HlBuf[2*32*1024];

  // W_hh B-fragments: wave's 16 gate rows, n=l15 -> W row g*512+U
  s16x8 wf[16];
  {
    const float* wr = Whh + (size_t)(g*512 + U)*512;
    #pragma unroll
    for (int ks=0; ks<16; ++ks){
      const float* s = wr + ks*32 + l4*8;
      f32x4 v0 = *(const f32x4*)s, v1 = *(const f32x4*)(s+4);
      s16x8 tt;
      tt[0]=(short)f2bf(v0[0]); tt[1]=(short)f2bf(v0[1]);
      tt[2]=(short)f2bf(v0[2]); tt[3]=(short)f2bf(v0[3]);
      tt[4]=(short)f2bf(v1[0]); tt[5]=(short)f2bf(v1[1]);
      tt[6]=(short)f2bf(v1[2]); tt[7]=(short)f2bf(v1[3]);
      wf[ks] = tt;
    }
  }

  // c-state restore (quad-redundant: 8 batches x own unit)
  float c[2][4];
  #pragma unroll
  for (int mt2=0; mt2<2; ++mt2)
    #pragma unroll
    for (int r=0; r<4; ++r)
      c[mt2][r] = cst[(size_t)(mt2*16 + l4*4 + r)*512 + U];

  for (int tt=0; tt<CHUNK; ++tt){
    const int t = t0 + tt;
    const unsigned long long Hs = (unsigned long long)(Hbuf + (size_t)(t & 3)*16384);
    unsigned short* Hd = Hbuf + (size_t)((t+1) & 3)*16384;
    char* Hl = HlBuf + (size_t)(t & 1)*32768;

    // xp gate inputs (cached; issued before the poll, complete during spin)
    float xg[2][4];
    #pragma unroll
    for (int mt2=0; mt2<2; ++mt2)
      #pragma unroll
      for (int r=0; r<4; ++r)
        xg[mt2][r] = bf2f(xp[(size_t)(tt*32 + mt2*16 + l4*4 + r)*2048 + gcol]);

    // poll flags (every wave independently; lanes 0..31)
    {
      u32 v;
      do {
        v = (lane < NBLK)
          ? __hip_atomic_load(&flag[lane<<5], __ATOMIC_RELAXED, __HIP_MEMORY_SCOPE_AGENT)
          : 0xffffffffu;
      } while (!__all(v >= (u32)t));
    }
    asm volatile("" ::: "memory");

    // coherent fetch (L1/L2 bypass => fresh, no fence) + swizzled LDS stage
    {
      f32x4 r0,r1,r2,r3,r4,r5,r6,r7;
      u32 o0 = (u32)(tid*16);
      u32 o1 = o0 +  4096, o2 = o0 +  8192, o3 = o0 + 12288;
      u32 o4 = o0 + 16384, o5 = o0 + 20480, o6 = o0 + 24576, o7 = o0 + 28672;
      asm volatile(
        "global_load_dwordx4 %0, %8, %16 sc0 sc1\n\t"
        "global_load_dwordx4 %1, %9, %16 sc0 sc1\n\t"
        "global_load_dwordx4 %2, %10, %16 sc0 sc1\n\t"
        "global_load_dwordx4 %3, %11, %16 sc0 sc1\n\t"
        "global_load_dwordx4 %4, %12, %16 sc0 sc1\n\t"
        "global_load_dwordx4 %5, %13, %16 sc0 sc1\n\t"
        "global_load_dwordx4 %6, %14, %16 sc0 sc1\n\t"
        "global_load_dwordx4 %7, %15, %16 sc0 sc1\n\t"
        "s_waitcnt vmcnt(0)"
        : "=&v"(r0), "=&v"(r1), "=&v"(r2), "=&v"(r3),
          "=&v"(r4), "=&v"(r5), "=&v"(r6), "=&v"(r7)
        : "v"(o0), "v"(o1), "v"(o2), "v"(o3),
          "v"(o4), "v"(o5), "v"(o6), "v"(o7), "s"(Hs)
        : "memory");
      __builtin_amdgcn_sched_barrier(0);
      int off = tid*16;
      *(f32x4*)&Hl[(off          ) ^ ((((off          )>>10)&7)<<4)] = r0;
      *(f32x4*)&Hl[(off +  4096  ) ^ ((((off +  4096  )>>10)&7)<<4)] = r1;
      *(f32x4*)&Hl[(off +  8192  ) ^ ((((off +  8192  )>>10)&7)<<4)] = r2;
      *(f32x4*)&Hl[(off + 12288  ) ^ ((((off + 12288  )>>10)&7)<<4)] = r3;
      *(f32x4*)&Hl[(off + 16384  ) ^ ((((off + 16384  )>>10)&7)<<4)] = r4;
      *(f32x4*)&Hl[(off + 20480  ) ^ ((((off + 20480  )>>10)&7)<<4)] = r5;
      *(f32x4*)&Hl[(off + 24576  ) ^ ((((off + 24576  )>>10)&7)<<4)] = r6;
      *(f32x4*)&Hl[(off + 28672  ) ^ ((((off + 28672  )>>10)&7)<<4)] = r7;
    }
    __syncthreads();

    // z = h_t @ Wslice^T : 2 m-tiles x 16 ks, A from swizzled LDS
    f32x4 z[2];
    #pragma unroll
    for (int mt2=0; mt2<2; ++mt2){
      const int row = mt2*16 + l15;
      const int swz = (row&7)<<4, rb = row<<10;
      f32x4 acc = (f32x4){0.f,0.f,0.f,0.f};
      #pragma unroll
      for (int ks=0; ks<16; ++ks){
        int cb = ks*64 + l4*16;
        s16x8 af = *(const s16x8*)(Hl + (rb | (cb ^ swz)));
        acc = MFMA16(af, wf[ks], acc);
      }
      z[mt2] = acc;
    }

    // gates: quad shfl exchange (lane holds gate g of its unit, 8 batches)
    float hv[2][4];
    #pragma unroll
    for (int mt2=0; mt2<2; ++mt2){
      #pragma unroll
      for (int r=0; r<4; ++r){
        float v = z[mt2][r] + xg[mt2][r];
        float vi = __shfl_xor(v, g    );
        float vf = __shfl_xor(v, g ^ 1);
        float vg = __shfl_xor(v, g ^ 2);
        float vo = __shfl_xor(v, g ^ 3);
        float ii = sigmoid_(vi), ff = sigmoid_(vf);
        float gg = tanh_(vg),    oo = sigmoid_(vo);
        float cc = ff*c[mt2][r] + ii*gg;
        c[mt2][r] = cc;
        hv[mt2][r] = oo * tanh_(cc);
      }
    }

    // select lane's 2 publish values (static indices only; g is runtime)
    float ha0 = (g&1) ? hv[0][2] : hv[0][0];
    float ha1 = (g&1) ? hv[0][3] : hv[0][1];
    float hb0 = (g&1) ? hv[1][2] : hv[1][0];
    float hb1 = (g&1) ? hv[1][3] : hv[1][1];
    float h0 = (g>>1) ? hb0 : ha0;   // h(bq,   U)
    float h1 = (g>>1) ? hb1 : ha1;   // h(bq+1, U)

    // pair units via shfl_xor(4): uq-even lanes store (U,U+1) packed u32
    {
      float p0 = __shfl_xor(h0, 4);
      float p1 = __shfl_xor(h1, 4);
      if ((uq & 1) == 0){
        u32 w0 = (u32)f2bf(h0) | ((u32)f2bf(p0) << 16);
        u32 w1 = (u32)f2bf(h1) | ((u32)f2bf(p1) << 16);
        __hip_atomic_store((u32*)(Hd + (size_t)(bq  )*512 + U), w0,
                           __ATOMIC_RELAXED, __HIP_MEMORY_SCOPE_AGENT);
        __hip_atomic_store((u32*)(Hd + (size_t)(bq+1)*512 + U), w1,
                           __ATOMIC_RELAXED, __HIP_MEMORY_SCOPE_AGENT);
      }
    }
    if (t == T_FULL-1){
      out[(size_t)(bq  )*512 + U] = h0;
      out[(size_t)(bq+1)*512 + U] = h1;
    }

    // drain own stores, block-wide, then publish flag
    asm volatile("s_waitcnt vmcnt(0)" ::: "memory");
    __syncthreads();
    if (tid == 0)
      __hip_atomic_store(&flag[k<<5], (u32)(t+1),
                         __ATOMIC_RELAXED, __HIP_MEMORY_SCOPE_AGENT);
  }

  // c-state save (lane's 2 assigned batches, own unit)
  {
    float ca0 = (g&1) ? c[0][2] : c[0][0];
    float ca1 = (g&1) ? c[0][3] : c[0][1];
    float cb0 = (g&1) ? c[1][2] : c[1][0];
    float cb1 = (g&1) ? c[1][3] : c[1][1];
    float c0s = (g>>1) ? cb0 : ca0;
    float c1s = (g>>1) ? cb1 : ca1;
    cst[(size_t)(bq  )*512 + U] = c0s;
    cst[(size_t)(bq+1)*512 + U] = c1s;
  }
}

// ---------------- launch ----------------
extern "C" void kernel_launch(void* const* d_in, const int* in_sizes, int n_in,
                              void* d_out, int out_size, void* d_ws, size_t ws_size,
                              hipStream_t stream)
{
  const float* x   = (const float*)d_in[0];
  const float* Wih = (const float*)d_in[1];
  const float* Whh = (const float*)d_in[2];
  const float* bih = (const float*)d_in[3];
  const float* bhh = (const float*)d_in[4];
  float* out = (float*)d_out;

  char* ws = (char*)d_ws;
  const size_t XP_BYTES = (size_t)CHUNK*32*2048*2;                  // 33,554,432
  unsigned short* xp   = (unsigned short*)ws;
  unsigned short* Hbuf = (unsigned short*)(ws + XP_BYTES);          // 4*32KB = 131072
  float*          cst  = (float*)(ws + XP_BYTES + 131072);          // 64KB
  u32*            flag = (u32*)(ws + XP_BYTES + 131072 + 65536);    // 32*128B = 4KB

  // zero Hbuf (h_0 = 0, all slots) + c-state + flags; every launch (replay-safe)
  (void)hipMemsetAsync(Hbuf, 0, 131072 + 65536 + 4096, stream);

  for (int c=0; c<NCHUNK; ++c){
    int t0 = c*CHUNK;
    lstm_p1<<<dim3(32, CHUNK*32/64), 256, 0, stream>>>(x, Wih, bih, bhh, xp, t0);
    lstm_p2<<<NBLK, 256, 0, stream>>>(xp, Whh, Hbuf, cst, flag, out, t0);
  }
}